// Round 1
// baseline (3474.318 us; speedup 1.0000x reference)
//
#include <hip/hip_runtime.h>

// PoissonPinn: d2u/dx2 of a [1,256,256,256,256,1] tanh MLP at N_EQ points
// (2nd-order forward-mode jet), plus plain forward at N_B boundary points.
//
// Parallelization: block = 256 threads = 4 independent waves.
// Each wave owns PW=4 points; each lane owns 4 hidden columns (lane+64c).
// Jet state (v, v', v'') per point lives in LDS ([P][256] fp32 each).
// Hidden GEMMs: z accumulators in registers; h via ds_read_b128 broadcast;
// W via coalesced global dwords (hot in L1/L2 — total W = 0.8 MB).

constexpr int HID = 256;
constexpr int PW  = 4;            // points per wave
constexpr int NW  = 4;            // waves per block
constexpr int P   = PW * NW;      // 16 points per block

__device__ __forceinline__ float fast_tanh(float x) {
    // tanh(x) = 1 - 2/(exp(2x)+1); stable for |x| large (exp->0 or inf)
    float e = __expf(2.0f * x);
    return 1.0f - 2.0f / (e + 1.0f);
}

__global__ __launch_bounds__(256, 3)
void pinn_eq_kernel(const float* __restrict__ x,
                    const float* __restrict__ W0, const float* __restrict__ b0,
                    const float* __restrict__ W1, const float* __restrict__ b1,
                    const float* __restrict__ W2, const float* __restrict__ b2,
                    const float* __restrict__ W3, const float* __restrict__ b3,
                    const float* __restrict__ W4,
                    float* __restrict__ out)
{
    __shared__ float HV[P][HID];   // value
    __shared__ float HD[P][HID];   // du/dx
    __shared__ float HS[P][HID];   // d2u/dx2

    const int lane  = threadIdx.x & 63;
    const int wv    = threadIdx.x >> 6;
    const int rbase = wv * PW;                  // first LDS row of this wave
    const int pbase = blockIdx.x * P + rbase;   // first point of this wave

    // ---- layer 0: scalar x -> 256 ----
    #pragma unroll
    for (int c = 0; c < 4; ++c) {
        const int   j  = lane + 64 * c;
        const float w  = W0[j];
        const float bb = b0[j];
        #pragma unroll
        for (int p = 0; p < PW; ++p) {
            const float xv = x[pbase + p];
            const float v  = fast_tanh(xv * w + bb);
            const float s2 = 1.0f - v * v;         // sech^2
            HV[rbase + p][j] = v;
            HD[rbase + p][j] = s2 * w;             // z'=w, z''=0
            HS[rbase + p][j] = -2.0f * v * s2 * w * w;
        }
    }
    __syncthreads();

    const float* Ws[3] = {W1, W2, W3};
    const float* bs[3] = {b1, b2, b3};

    #pragma unroll
    for (int l = 0; l < 3; ++l) {
        const float* __restrict__ W = Ws[l];
        const float* __restrict__ b = bs[l];

        float zv[PW][4], zd[PW][4], zs[PW][4];
        #pragma unroll
        for (int p = 0; p < PW; ++p)
            #pragma unroll
            for (int c = 0; c < 4; ++c) {
                zv[p][c] = b[lane + 64 * c];
                zd[p][c] = 0.0f;
                zs[p][c] = 0.0f;
            }

        for (int i = 0; i < HID; i += 4) {
            float w[4][4];
            #pragma unroll
            for (int q = 0; q < 4; ++q)
                #pragma unroll
                for (int c = 0; c < 4; ++c)
                    w[q][c] = W[(i + q) * HID + lane + 64 * c];

            #pragma unroll
            for (int p = 0; p < PW; ++p) {
                const float4 av = *(const float4*)&HV[rbase + p][i];
                const float4 ad = *(const float4*)&HD[rbase + p][i];
                const float4 as = *(const float4*)&HS[rbase + p][i];
                #pragma unroll
                for (int q = 0; q < 4; ++q) {
                    const float a_v = ((const float*)&av)[q];
                    const float a_d = ((const float*)&ad)[q];
                    const float a_s = ((const float*)&as)[q];
                    #pragma unroll
                    for (int c = 0; c < 4; ++c) {
                        zv[p][c] = fmaf(a_v, w[q][c], zv[p][c]);
                        zd[p][c] = fmaf(a_d, w[q][c], zd[p][c]);
                        zs[p][c] = fmaf(a_s, w[q][c], zs[p][c]);
                    }
                }
            }
        }
        __syncthreads();   // reads of H* complete before overwrite

        #pragma unroll
        for (int p = 0; p < PW; ++p)
            #pragma unroll
            for (int c = 0; c < 4; ++c) {
                const int   j  = lane + 64 * c;
                const float v  = fast_tanh(zv[p][c]);
                const float s2 = 1.0f - v * v;
                const float dd = zd[p][c];
                HV[rbase + p][j] = v;
                HD[rbase + p][j] = s2 * dd;
                HS[rbase + p][j] = s2 * zs[p][c] - 2.0f * v * s2 * dd * dd;
            }
        __syncthreads();   // writes visible before next layer's reads
    }

    // ---- output layer (linear): d2u = s3 @ W4 ----
    #pragma unroll
    for (int p = 0; p < PW; ++p) {
        float acc = 0.0f;
        #pragma unroll
        for (int c = 0; c < 4; ++c) {
            const int j = lane + 64 * c;
            acc = fmaf(HS[rbase + p][j], W4[j], acc);
        }
        #pragma unroll
        for (int off = 32; off > 0; off >>= 1)
            acc += __shfl_down(acc, off, 64);
        if (lane == 0) out[pbase + p] = acc;
    }
}

__global__ __launch_bounds__(256, 3)
void pinn_bnd_kernel(const float* __restrict__ x,
                     const float* __restrict__ W0, const float* __restrict__ b0,
                     const float* __restrict__ W1, const float* __restrict__ b1,
                     const float* __restrict__ W2, const float* __restrict__ b2,
                     const float* __restrict__ W3, const float* __restrict__ b3,
                     const float* __restrict__ W4, const float* __restrict__ b4,
                     float* __restrict__ out)
{
    __shared__ float HV[P][HID];

    const int lane  = threadIdx.x & 63;
    const int wv    = threadIdx.x >> 6;
    const int rbase = wv * PW;
    const int pbase = blockIdx.x * P + rbase;

    #pragma unroll
    for (int c = 0; c < 4; ++c) {
        const int   j  = lane + 64 * c;
        const float w  = W0[j];
        const float bb = b0[j];
        #pragma unroll
        for (int p = 0; p < PW; ++p) {
            HV[rbase + p][j] = fast_tanh(x[pbase + p] * w + bb);
        }
    }
    __syncthreads();

    const float* Ws[3] = {W1, W2, W3};
    const float* bs[3] = {b1, b2, b3};

    #pragma unroll
    for (int l = 0; l < 3; ++l) {
        const float* __restrict__ W = Ws[l];
        const float* __restrict__ b = bs[l];

        float zv[PW][4];
        #pragma unroll
        for (int p = 0; p < PW; ++p)
            #pragma unroll
            for (int c = 0; c < 4; ++c)
                zv[p][c] = b[lane + 64 * c];

        for (int i = 0; i < HID; i += 4) {
            float w[4][4];
            #pragma unroll
            for (int q = 0; q < 4; ++q)
                #pragma unroll
                for (int c = 0; c < 4; ++c)
                    w[q][c] = W[(i + q) * HID + lane + 64 * c];

            #pragma unroll
            for (int p = 0; p < PW; ++p) {
                const float4 av = *(const float4*)&HV[rbase + p][i];
                #pragma unroll
                for (int q = 0; q < 4; ++q) {
                    const float a_v = ((const float*)&av)[q];
                    #pragma unroll
                    for (int c = 0; c < 4; ++c)
                        zv[p][c] = fmaf(a_v, w[q][c], zv[p][c]);
                }
            }
        }
        __syncthreads();

        #pragma unroll
        for (int p = 0; p < PW; ++p)
            #pragma unroll
            for (int c = 0; c < 4; ++c)
                HV[rbase + p][lane + 64 * c] = fast_tanh(zv[p][c]);
        __syncthreads();
    }

    const float bias4 = b4[0];
    #pragma unroll
    for (int p = 0; p < PW; ++p) {
        float acc = 0.0f;
        #pragma unroll
        for (int c = 0; c < 4; ++c) {
            const int j = lane + 64 * c;
            acc = fmaf(HV[rbase + p][j], W4[j], acc);
        }
        #pragma unroll
        for (int off = 32; off > 0; off >>= 1)
            acc += __shfl_down(acc, off, 64);
        if (lane == 0) out[pbase + p] = acc + bias4;
    }
}

extern "C" void kernel_launch(void* const* d_in, const int* in_sizes, int n_in,
                              void* d_out, int out_size, void* d_ws, size_t ws_size,
                              hipStream_t stream) {
    const float* xe = (const float*)d_in[0];
    const float* xb = (const float*)d_in[1];
    const float* W0 = (const float*)d_in[2];
    const float* b0 = (const float*)d_in[3];
    const float* W1 = (const float*)d_in[4];
    const float* b1 = (const float*)d_in[5];
    const float* W2 = (const float*)d_in[6];
    const float* b2 = (const float*)d_in[7];
    const float* W3 = (const float*)d_in[8];
    const float* b3 = (const float*)d_in[9];
    const float* W4 = (const float*)d_in[10];
    const float* b4 = (const float*)d_in[11];
    float* out = (float*)d_out;

    const int n_eq = in_sizes[0];   // 262144
    const int n_b  = in_sizes[1];   // 8192

    pinn_eq_kernel<<<n_eq / P, NW * 64, 0, stream>>>(
        xe, W0, b0, W1, b1, W2, b2, W3, b3, W4, out);
    pinn_bnd_kernel<<<n_b / P, NW * 64, 0, stream>>>(
        xb, W0, b0, W1, b1, W2, b2, W3, b3, W4, b4, out + n_eq);
}

// Round 2
// 1692.785 us; speedup vs baseline: 2.0524x; 2.0524x over previous
//
#include <hip/hip_runtime.h>

// PoissonPinn via 2nd-order forward-mode jet, hidden GEMMs on bf16 MFMA
// with hi/lo split-precision (3 MFMA terms: Ah*Bh + Ah*Bl + Al*Bh).
//
// Block = 256 threads (4 waves) handles MPTS=16 points = 48 jet rows:
//   rows 0..15 = v, 16..31 = v', 32..47 = v''  (m-tiles 0,1,2)
// Jet state in LDS as bf16 hi+lo [48][256+8] (pad -> conflict-free-ish).
// Each wave owns 4 n-tiles (64 output cols) x all 3 m-tiles:
//   12 C-tiles * f32x4 = 48 acc regs; K-loop: 8 steps of K=32.
// A-frags: ds_read_b128 from LDS. B-frags: 16B/lane global from Wt[n][k]
// (hi/lo, transposed+split by prep kernel into d_ws; W read once/block/layer).

constexpr int HID   = 256;
constexpr int MPTS  = 16;              // points per block (eq kernel)
constexpr int LDP   = HID + 8;         // padded LDS row stride (bf16 elems)
constexpr int WELEM = 3 * HID * HID;   // elems per split array in ws

typedef __bf16 bf16x8 __attribute__((ext_vector_type(8)));
typedef float  f32x4  __attribute__((ext_vector_type(4)));

__device__ __forceinline__ float fast_tanh(float x) {
    float e = __expf(2.0f * x);
    return 1.0f - 2.0f / (e + 1.0f);
}

// ---- prep: W1..W3 (fp32 [k][n]) -> transposed bf16 hi/lo Wt[l][n][k] ----
__global__ void prep_w(const float* __restrict__ W1,
                       const float* __restrict__ W2,
                       const float* __restrict__ W3,
                       __bf16* __restrict__ Wh, __bf16* __restrict__ Wl) {
    const int idx = blockIdx.x * 256 + threadIdx.x;   // 0 .. 3*65536-1
    const int l = idx >> 16;
    const int r = idx & 0xFFFF;
    const int n = r >> 8;
    const int k = r & 0xFF;
    const float* W = (l == 0) ? W1 : (l == 1) ? W2 : W3;
    const float w  = W[k * HID + n];
    const __bf16 hi = (__bf16)w;
    const __bf16 lo = (__bf16)(w - (float)hi);
    Wh[idx] = hi;
    Wl[idx] = lo;
}

__global__ __launch_bounds__(256, 3)
void pinn_eq_mfma(const float* __restrict__ x,
                  const float* __restrict__ W0, const float* __restrict__ b0,
                  const float* __restrict__ b1, const float* __restrict__ b2,
                  const float* __restrict__ b3, const float* __restrict__ W4,
                  const __bf16* __restrict__ Wh, const __bf16* __restrict__ Wl,
                  float* __restrict__ out)
{
    __shared__ __align__(16) __bf16 Hh[3 * MPTS][LDP];
    __shared__ __align__(16) __bf16 Hl[3 * MPTS][LDP];

    const int tid  = threadIdx.x;
    const int lane = tid & 63;
    const int wv   = tid >> 6;
    const int m    = lane & 15;     // A-frag row / C col
    const int q    = lane >> 4;     // quad: A/B k-group, C row-group
    const int pb   = blockIdx.x * MPTS;

    // ---- layer 0: col c = tid, all 16 points ----
    {
        const int   c  = tid;
        const float w  = W0[c];
        const float bb = b0[c];
        #pragma unroll
        for (int p = 0; p < MPTS; ++p) {
            const float xv = x[pb + p];
            const float v  = fast_tanh(xv * w + bb);
            const float s2 = 1.0f - v * v;
            const float d  = s2 * w;
            const float s  = -2.0f * v * s2 * w * w;
            const __bf16 vh = (__bf16)v;  const __bf16 vl = (__bf16)(v - (float)vh);
            const __bf16 dh = (__bf16)d;  const __bf16 dl = (__bf16)(d - (float)dh);
            const __bf16 sh = (__bf16)s;  const __bf16 sl = (__bf16)(s - (float)sh);
            Hh[p][c]            = vh;  Hl[p][c]            = vl;
            Hh[MPTS + p][c]     = dh;  Hl[MPTS + p][c]     = dl;
            Hh[2 * MPTS + p][c] = sh;  Hl[2 * MPTS + p][c] = sl;
        }
    }
    __syncthreads();

    const float* bias[3] = {b1, b2, b3};

    for (int l = 0; l < 3; ++l) {
        const __bf16* __restrict__ wh = Wh + l * HID * HID;
        const __bf16* __restrict__ wl = Wl + l * HID * HID;

        f32x4 accv[4], accd[4], accs[4];
        #pragma unroll
        for (int nt = 0; nt < 4; ++nt) {
            accv[nt] = (f32x4)0.0f;
            accd[nt] = (f32x4)0.0f;
            accs[nt] = (f32x4)0.0f;
        }

        for (int ks = 0; ks < 8; ++ks) {
            const int kk = ks * 32 + q * 8;

            bf16x8 ah[3], al[3];
            #pragma unroll
            for (int mt = 0; mt < 3; ++mt) {
                ah[mt] = *(const bf16x8*)&Hh[mt * MPTS + m][kk];
                al[mt] = *(const bf16x8*)&Hl[mt * MPTS + m][kk];
            }

            bf16x8 bh[4], bl[4];
            #pragma unroll
            for (int nt = 0; nt < 4; ++nt) {
                const int n = (wv * 4 + nt) * 16 + m;
                bh[nt] = *(const bf16x8*)&wh[n * HID + kk];
                bl[nt] = *(const bf16x8*)&wl[n * HID + kk];
            }

            #pragma unroll
            for (int nt = 0; nt < 4; ++nt) {
                accv[nt] = __builtin_amdgcn_mfma_f32_16x16x32_bf16(ah[0], bh[nt], accv[nt], 0, 0, 0);
                accd[nt] = __builtin_amdgcn_mfma_f32_16x16x32_bf16(ah[1], bh[nt], accd[nt], 0, 0, 0);
                accs[nt] = __builtin_amdgcn_mfma_f32_16x16x32_bf16(ah[2], bh[nt], accs[nt], 0, 0, 0);
                accv[nt] = __builtin_amdgcn_mfma_f32_16x16x32_bf16(ah[0], bl[nt], accv[nt], 0, 0, 0);
                accd[nt] = __builtin_amdgcn_mfma_f32_16x16x32_bf16(ah[1], bl[nt], accd[nt], 0, 0, 0);
                accs[nt] = __builtin_amdgcn_mfma_f32_16x16x32_bf16(ah[2], bl[nt], accs[nt], 0, 0, 0);
                accv[nt] = __builtin_amdgcn_mfma_f32_16x16x32_bf16(al[0], bh[nt], accv[nt], 0, 0, 0);
                accd[nt] = __builtin_amdgcn_mfma_f32_16x16x32_bf16(al[1], bh[nt], accd[nt], 0, 0, 0);
                accs[nt] = __builtin_amdgcn_mfma_f32_16x16x32_bf16(al[2], bh[nt], accs[nt], 0, 0, 0);
            }
        }

        // ---- jet epilogue (register-only), then LDS writeback ----
        const float* __restrict__ bvec = bias[l];
        float nv[4][4], nd[4][4], ns[4][4];
        #pragma unroll
        for (int nt = 0; nt < 4; ++nt) {
            const int col = (wv * 4 + nt) * 16 + m;
            const float bb = bvec[col];
            #pragma unroll
            for (int r = 0; r < 4; ++r) {
                const float zv = accv[nt][r] + bb;
                const float zd = accd[nt][r];
                const float zs = accs[nt][r];
                const float v  = fast_tanh(zv);
                const float s2 = 1.0f - v * v;
                nv[nt][r] = v;
                nd[nt][r] = s2 * zd;
                ns[nt][r] = s2 * zs - 2.0f * v * s2 * zd * zd;
            }
        }
        __syncthreads();   // all waves done READING H for this layer
        #pragma unroll
        for (int nt = 0; nt < 4; ++nt) {
            const int col = (wv * 4 + nt) * 16 + m;
            #pragma unroll
            for (int r = 0; r < 4; ++r) {
                const int pt = q * 4 + r;
                const float v = nv[nt][r], d = nd[nt][r], s = ns[nt][r];
                const __bf16 vh = (__bf16)v;  const __bf16 vl = (__bf16)(v - (float)vh);
                const __bf16 dh = (__bf16)d;  const __bf16 dl = (__bf16)(d - (float)dh);
                const __bf16 sh = (__bf16)s;  const __bf16 sl = (__bf16)(s - (float)sh);
                Hh[pt][col]            = vh;  Hl[pt][col]            = vl;
                Hh[MPTS + pt][col]     = dh;  Hl[MPTS + pt][col]     = dl;
                Hh[2 * MPTS + pt][col] = sh;  Hl[2 * MPTS + pt][col] = sl;
            }
        }
        __syncthreads();   // writes visible before next layer / final dot
    }

    // ---- final: d2u[pt] = sum_j h''[pt][j] * W4[j] ----
    {
        const int pt = tid >> 4;
        const int cc = tid & 15;
        float acc = 0.0f;
        #pragma unroll
        for (int j = 0; j < 16; ++j) {
            const int col = cc * 16 + j;
            const float hv = (float)Hh[2 * MPTS + pt][col] + (float)Hl[2 * MPTS + pt][col];
            acc = fmaf(hv, W4[col], acc);
        }
        #pragma unroll
        for (int off = 8; off > 0; off >>= 1)
            acc += __shfl_down(acc, off, 64);
        if (cc == 0) out[pb + pt] = acc;
    }
}

// ---- boundary: plain fp32 vector forward (tiny: 8192 points) ----
constexpr int BPW = 4;
constexpr int BP  = 16;

__global__ __launch_bounds__(256, 3)
void pinn_bnd_kernel(const float* __restrict__ x,
                     const float* __restrict__ W0, const float* __restrict__ b0,
                     const float* __restrict__ W1, const float* __restrict__ b1,
                     const float* __restrict__ W2, const float* __restrict__ b2,
                     const float* __restrict__ W3, const float* __restrict__ b3,
                     const float* __restrict__ W4, const float* __restrict__ b4,
                     float* __restrict__ out)
{
    __shared__ float HV[BP][HID];

    const int lane  = threadIdx.x & 63;
    const int wv    = threadIdx.x >> 6;
    const int rbase = wv * BPW;
    const int pbase = blockIdx.x * BP + rbase;

    #pragma unroll
    for (int c = 0; c < 4; ++c) {
        const int   j  = lane + 64 * c;
        const float w  = W0[j];
        const float bb = b0[j];
        #pragma unroll
        for (int p = 0; p < BPW; ++p)
            HV[rbase + p][j] = fast_tanh(x[pbase + p] * w + bb);
    }
    __syncthreads();

    const float* Ws[3] = {W1, W2, W3};
    const float* bs[3] = {b1, b2, b3};

    #pragma unroll
    for (int l = 0; l < 3; ++l) {
        const float* __restrict__ W = Ws[l];
        const float* __restrict__ b = bs[l];

        float zv[BPW][4];
        #pragma unroll
        for (int p = 0; p < BPW; ++p)
            #pragma unroll
            for (int c = 0; c < 4; ++c)
                zv[p][c] = b[lane + 64 * c];

        for (int i = 0; i < HID; i += 4) {
            float w[4][4];
            #pragma unroll
            for (int qq = 0; qq < 4; ++qq)
                #pragma unroll
                for (int c = 0; c < 4; ++c)
                    w[qq][c] = W[(i + qq) * HID + lane + 64 * c];

            #pragma unroll
            for (int p = 0; p < BPW; ++p) {
                const float4 av = *(const float4*)&HV[rbase + p][i];
                #pragma unroll
                for (int qq = 0; qq < 4; ++qq) {
                    const float a_v = ((const float*)&av)[qq];
                    #pragma unroll
                    for (int c = 0; c < 4; ++c)
                        zv[p][c] = fmaf(a_v, w[qq][c], zv[p][c]);
                }
            }
        }
        __syncthreads();

        #pragma unroll
        for (int p = 0; p < BPW; ++p)
            #pragma unroll
            for (int c = 0; c < 4; ++c)
                HV[rbase + p][lane + 64 * c] = fast_tanh(zv[p][c]);
        __syncthreads();
    }

    const float bias4 = b4[0];
    #pragma unroll
    for (int p = 0; p < BPW; ++p) {
        float acc = 0.0f;
        #pragma unroll
        for (int c = 0; c < 4; ++c) {
            const int j = lane + 64 * c;
            acc = fmaf(HV[rbase + p][j], W4[j], acc);
        }
        #pragma unroll
        for (int off = 32; off > 0; off >>= 1)
            acc += __shfl_down(acc, off, 64);
        if (lane == 0) out[pbase + p] = acc + bias4;
    }
}

extern "C" void kernel_launch(void* const* d_in, const int* in_sizes, int n_in,
                              void* d_out, int out_size, void* d_ws, size_t ws_size,
                              hipStream_t stream) {
    const float* xe = (const float*)d_in[0];
    const float* xb = (const float*)d_in[1];
    const float* W0 = (const float*)d_in[2];
    const float* b0 = (const float*)d_in[3];
    const float* W1 = (const float*)d_in[4];
    const float* b1 = (const float*)d_in[5];
    const float* W2 = (const float*)d_in[6];
    const float* b2 = (const float*)d_in[7];
    const float* W3 = (const float*)d_in[8];
    const float* b3 = (const float*)d_in[9];
    const float* W4 = (const float*)d_in[10];
    const float* b4 = (const float*)d_in[11];
    float* out = (float*)d_out;

    const int n_eq = in_sizes[0];   // 262144
    const int n_b  = in_sizes[1];   // 8192

    __bf16* Wh = (__bf16*)d_ws;                    // 3*256*256 bf16 = 384 KB
    __bf16* Wl = Wh + WELEM;                       // another 384 KB

    prep_w<<<WELEM / 256, 256, 0, stream>>>(W1, W2, W3, Wh, Wl);

    pinn_eq_mfma<<<n_eq / MPTS, 256, 0, stream>>>(
        xe, W0, b0, b1, b2, b3, W4, Wh, Wl, out);

    pinn_bnd_kernel<<<n_b / BP, 256, 0, stream>>>(
        xb, W0, b0, W1, b1, W2, b2, W3, b3, W4, b4, out + n_eq);
}

// Round 3
// 1401.544 us; speedup vs baseline: 2.4789x; 1.2078x over previous
//
#include <hip/hip_runtime.h>

// PoissonPinn via 2nd-order forward-mode jet, hidden GEMMs on bf16 MFMA
// with hi/lo split-precision (3 MFMA terms: Ah*Bh + Ah*Bl + Al*Bh).
//
// Round-3 changes vs round-2:
//  * W pre-swizzled into MFMA fragment order Wf[l][n0][ks][lane][j] so each
//    B-frag load is one coalesced 1KB wave read (was 16 scattered rows).
//  * B-frags double-buffered: prefetch ks+1 during ks's MFMAs; prefetch the
//    next layer's ks=0 before the epilogue barriers.
//  * MFMA burst ordered by term (hh,hl,lh): same-acc dep spacing 12.

constexpr int HID   = 256;
constexpr int MPTS  = 16;              // points per block (eq kernel)
constexpr int LDP   = HID + 8;         // padded LDS row stride (bf16 elems)
constexpr int WELEM = 3 * HID * HID;   // elems per split array in ws

typedef __bf16 bf16x8 __attribute__((ext_vector_type(8)));
typedef float  f32x4  __attribute__((ext_vector_type(4)));

__device__ __forceinline__ float fast_tanh(float x) {
    float e = __expf(2.0f * x);
    return 1.0f - 2.0f / (e + 1.0f);
}

// ---- prep: W1..W3 (fp32 [k][n]) -> bf16 hi/lo in fragment order ----
// Wf[l][n0][ks][lane][j]: lane=q*16+m reads W[k=ks*32+q*8+j][n=n0*16+m]
__global__ void prep_w(const float* __restrict__ W1,
                       const float* __restrict__ W2,
                       const float* __restrict__ W3,
                       __bf16* __restrict__ Wh, __bf16* __restrict__ Wl) {
    const int idx = blockIdx.x * 256 + threadIdx.x;   // 0 .. WELEM-1
    const int l   = idx >> 16;
    const int r   = idx & 0xFFFF;
    const int n0  = r >> 12;
    const int ks  = (r >> 9) & 7;
    const int ln  = (r >> 3) & 63;
    const int j   = r & 7;
    const int mm  = ln & 15;
    const int qq  = ln >> 4;
    const int k   = ks * 32 + qq * 8 + j;
    const int n   = n0 * 16 + mm;
    const float* W = (l == 0) ? W1 : (l == 1) ? W2 : W3;
    const float w  = W[k * HID + n];
    const __bf16 hi = (__bf16)w;
    Wh[idx] = hi;
    Wl[idx] = (__bf16)(w - (float)hi);
}

__global__ __launch_bounds__(256, 3)
void pinn_eq_mfma(const float* __restrict__ x,
                  const float* __restrict__ W0, const float* __restrict__ b0,
                  const float* __restrict__ b1, const float* __restrict__ b2,
                  const float* __restrict__ b3, const float* __restrict__ W4,
                  const __bf16* __restrict__ Wh, const __bf16* __restrict__ Wl,
                  float* __restrict__ out)
{
    __shared__ __align__(16) __bf16 Hh[3 * MPTS][LDP];
    __shared__ __align__(16) __bf16 Hl[3 * MPTS][LDP];

    const int tid  = threadIdx.x;
    const int lane = tid & 63;
    const int wv   = tid >> 6;
    const int m    = lane & 15;     // A-frag row / C col
    const int q    = lane >> 4;     // quad
    const int pb   = blockIdx.x * MPTS;

    bf16x8 AH[3], AL[3], BH0[4], BL0[4], BH1[4], BL1[4];
    f32x4  accv[4], accd[4], accs[4];

    auto loadB = [&](bf16x8* BH, bf16x8* BL,
                     const __bf16* whB, const __bf16* wlB, int ks) {
        #pragma unroll
        for (int nt = 0; nt < 4; ++nt) {
            const int off = ((wv * 4 + nt) * 8 + ks) * 512 + lane * 8;
            BH[nt] = *(const bf16x8*)(whB + off);
            BL[nt] = *(const bf16x8*)(wlB + off);
        }
    };
    auto loadA = [&](int ks) {
        const int kk = ks * 32 + q * 8;
        #pragma unroll
        for (int mt = 0; mt < 3; ++mt) {
            AH[mt] = *(const bf16x8*)&Hh[mt * MPTS + m][kk];
            AL[mt] = *(const bf16x8*)&Hl[mt * MPTS + m][kk];
        }
    };
    auto mfma36 = [&](bf16x8* BH, bf16x8* BL) {
        #pragma unroll
        for (int nt = 0; nt < 4; ++nt) {
            accv[nt] = __builtin_amdgcn_mfma_f32_16x16x32_bf16(AH[0], BH[nt], accv[nt], 0, 0, 0);
            accd[nt] = __builtin_amdgcn_mfma_f32_16x16x32_bf16(AH[1], BH[nt], accd[nt], 0, 0, 0);
            accs[nt] = __builtin_amdgcn_mfma_f32_16x16x32_bf16(AH[2], BH[nt], accs[nt], 0, 0, 0);
        }
        #pragma unroll
        for (int nt = 0; nt < 4; ++nt) {
            accv[nt] = __builtin_amdgcn_mfma_f32_16x16x32_bf16(AH[0], BL[nt], accv[nt], 0, 0, 0);
            accd[nt] = __builtin_amdgcn_mfma_f32_16x16x32_bf16(AH[1], BL[nt], accd[nt], 0, 0, 0);
            accs[nt] = __builtin_amdgcn_mfma_f32_16x16x32_bf16(AH[2], BL[nt], accs[nt], 0, 0, 0);
        }
        #pragma unroll
        for (int nt = 0; nt < 4; ++nt) {
            accv[nt] = __builtin_amdgcn_mfma_f32_16x16x32_bf16(AL[0], BH[nt], accv[nt], 0, 0, 0);
            accd[nt] = __builtin_amdgcn_mfma_f32_16x16x32_bf16(AL[1], BH[nt], accd[nt], 0, 0, 0);
            accs[nt] = __builtin_amdgcn_mfma_f32_16x16x32_bf16(AL[2], BH[nt], accs[nt], 0, 0, 0);
        }
    };

    // earliest possible: layer-1 ks=0 B-frags in flight during layer 0
    loadB(BH0, BL0, Wh, Wl, 0);

    // ---- layer 0: col c = tid, all 16 points ----
    {
        const int   c  = tid;
        const float w  = W0[c];
        const float bb = b0[c];
        #pragma unroll
        for (int p = 0; p < MPTS; ++p) {
            const float xv = x[pb + p];
            const float v  = fast_tanh(xv * w + bb);
            const float s2 = 1.0f - v * v;
            const float d  = s2 * w;
            const float s  = -2.0f * v * s2 * w * w;
            const __bf16 vh = (__bf16)v;  const __bf16 vl = (__bf16)(v - (float)vh);
            const __bf16 dh = (__bf16)d;  const __bf16 dl = (__bf16)(d - (float)dh);
            const __bf16 sh = (__bf16)s;  const __bf16 sl = (__bf16)(s - (float)sh);
            Hh[p][c]            = vh;  Hl[p][c]            = vl;
            Hh[MPTS + p][c]     = dh;  Hl[MPTS + p][c]     = dl;
            Hh[2 * MPTS + p][c] = sh;  Hl[2 * MPTS + p][c] = sl;
        }
    }
    __syncthreads();

    const float* bias[3] = {b1, b2, b3};

    for (int l = 0; l < 3; ++l) {
        const __bf16* __restrict__ whB = Wh + l * HID * HID;
        const __bf16* __restrict__ wlB = Wl + l * HID * HID;

        #pragma unroll
        for (int nt = 0; nt < 4; ++nt) {
            accv[nt] = (f32x4)0.0f;
            accd[nt] = (f32x4)0.0f;
            accs[nt] = (f32x4)0.0f;
        }

        loadA(0);
        #pragma unroll 1
        for (int ks = 0; ks < 8; ks += 2) {
            loadB(BH1, BL1, whB, wlB, ks + 1);       // prefetch odd step
            mfma36(BH0, BL0);
            loadA(ks + 1);
            if (ks + 2 < 8) loadB(BH0, BL0, whB, wlB, ks + 2);  // prefetch even
            mfma36(BH1, BL1);
            if (ks + 2 < 8) loadA(ks + 2);
        }

        // prefetch next layer's first B-frags; latency hides behind epilogue
        if (l < 2) loadB(BH0, BL0, whB + HID * HID, wlB + HID * HID, 0);

        // ---- jet epilogue (register-only), then LDS writeback ----
        const float* __restrict__ bvec = bias[l];
        float nv[4][4], nd[4][4], ns[4][4];
        #pragma unroll
        for (int nt = 0; nt < 4; ++nt) {
            const int col = (wv * 4 + nt) * 16 + m;
            const float bb = bvec[col];
            #pragma unroll
            for (int r = 0; r < 4; ++r) {
                const float zv = accv[nt][r] + bb;
                const float zd = accd[nt][r];
                const float zs = accs[nt][r];
                const float v  = fast_tanh(zv);
                const float s2 = 1.0f - v * v;
                nv[nt][r] = v;
                nd[nt][r] = s2 * zd;
                ns[nt][r] = s2 * zs - 2.0f * v * s2 * zd * zd;
            }
        }
        __syncthreads();   // all waves done READING H for this layer
        #pragma unroll
        for (int nt = 0; nt < 4; ++nt) {
            const int col = (wv * 4 + nt) * 16 + m;
            #pragma unroll
            for (int r = 0; r < 4; ++r) {
                const int pt = q * 4 + r;
                const float v = nv[nt][r], d = nd[nt][r], s = ns[nt][r];
                const __bf16 vh = (__bf16)v;  const __bf16 vl = (__bf16)(v - (float)vh);
                const __bf16 dh = (__bf16)d;  const __bf16 dl = (__bf16)(d - (float)dh);
                const __bf16 sh = (__bf16)s;  const __bf16 sl = (__bf16)(s - (float)sh);
                Hh[pt][col]            = vh;  Hl[pt][col]            = vl;
                Hh[MPTS + pt][col]     = dh;  Hl[MPTS + pt][col]     = dl;
                Hh[2 * MPTS + pt][col] = sh;  Hl[2 * MPTS + pt][col] = sl;
            }
        }
        __syncthreads();   // writes visible before next layer / final dot
    }

    // ---- final: d2u[pt] = sum_j h''[pt][j] * W4[j] ----
    {
        const int pt = tid >> 4;
        const int cc = tid & 15;
        float acc = 0.0f;
        #pragma unroll
        for (int j = 0; j < 16; ++j) {
            const int col = cc * 16 + j;
            const float hv = (float)Hh[2 * MPTS + pt][col] + (float)Hl[2 * MPTS + pt][col];
            acc = fmaf(hv, W4[col], acc);
        }
        #pragma unroll
        for (int off = 8; off > 0; off >>= 1)
            acc += __shfl_down(acc, off, 64);
        if (cc == 0) out[pb + pt] = acc;
    }
}

// ---- boundary: plain fp32 vector forward (tiny: 8192 points) ----
constexpr int BPW = 4;
constexpr int BP  = 16;

__global__ __launch_bounds__(256, 3)
void pinn_bnd_kernel(const float* __restrict__ x,
                     const float* __restrict__ W0, const float* __restrict__ b0,
                     const float* __restrict__ W1, const float* __restrict__ b1,
                     const float* __restrict__ W2, const float* __restrict__ b2,
                     const float* __restrict__ W3, const float* __restrict__ b3,
                     const float* __restrict__ W4, const float* __restrict__ b4,
                     float* __restrict__ out)
{
    __shared__ float HV[BP][HID];

    const int lane  = threadIdx.x & 63;
    const int wv    = threadIdx.x >> 6;
    const int rbase = wv * BPW;
    const int pbase = blockIdx.x * BP + rbase;

    #pragma unroll
    for (int c = 0; c < 4; ++c) {
        const int   j  = lane + 64 * c;
        const float w  = W0[j];
        const float bb = b0[j];
        #pragma unroll
        for (int p = 0; p < BPW; ++p)
            HV[rbase + p][j] = fast_tanh(x[pbase + p] * w + bb);
    }
    __syncthreads();

    const float* Ws[3] = {W1, W2, W3};
    const float* bs[3] = {b1, b2, b3};

    #pragma unroll
    for (int l = 0; l < 3; ++l) {
        const float* __restrict__ W = Ws[l];
        const float* __restrict__ b = bs[l];

        float zv[BPW][4];
        #pragma unroll
        for (int p = 0; p < BPW; ++p)
            #pragma unroll
            for (int c = 0; c < 4; ++c)
                zv[p][c] = b[lane + 64 * c];

        for (int i = 0; i < HID; i += 4) {
            float w[4][4];
            #pragma unroll
            for (int qq = 0; qq < 4; ++qq)
                #pragma unroll
                for (int c = 0; c < 4; ++c)
                    w[qq][c] = W[(i + qq) * HID + lane + 64 * c];

            #pragma unroll
            for (int p = 0; p < BPW; ++p) {
                const float4 av = *(const float4*)&HV[rbase + p][i];
                #pragma unroll
                for (int qq = 0; qq < 4; ++qq) {
                    const float a_v = ((const float*)&av)[qq];
                    #pragma unroll
                    for (int c = 0; c < 4; ++c)
                        zv[p][c] = fmaf(a_v, w[qq][c], zv[p][c]);
                }
            }
        }
        __syncthreads();

        #pragma unroll
        for (int p = 0; p < BPW; ++p)
            #pragma unroll
            for (int c = 0; c < 4; ++c)
                HV[rbase + p][lane + 64 * c] = fast_tanh(zv[p][c]);
        __syncthreads();
    }

    const float bias4 = b4[0];
    #pragma unroll
    for (int p = 0; p < BPW; ++p) {
        float acc = 0.0f;
        #pragma unroll
        for (int c = 0; c < 4; ++c) {
            const int j = lane + 64 * c;
            acc = fmaf(HV[rbase + p][j], W4[j], acc);
        }
        #pragma unroll
        for (int off = 32; off > 0; off >>= 1)
            acc += __shfl_down(acc, off, 64);
        if (lane == 0) out[pbase + p] = acc + bias4;
    }
}

extern "C" void kernel_launch(void* const* d_in, const int* in_sizes, int n_in,
                              void* d_out, int out_size, void* d_ws, size_t ws_size,
                              hipStream_t stream) {
    const float* xe = (const float*)d_in[0];
    const float* xb = (const float*)d_in[1];
    const float* W0 = (const float*)d_in[2];
    const float* b0 = (const float*)d_in[3];
    const float* W1 = (const float*)d_in[4];
    const float* b1 = (const float*)d_in[5];
    const float* W2 = (const float*)d_in[6];
    const float* b2 = (const float*)d_in[7];
    const float* W3 = (const float*)d_in[8];
    const float* b3 = (const float*)d_in[9];
    const float* W4 = (const float*)d_in[10];
    const float* b4 = (const float*)d_in[11];
    float* out = (float*)d_out;

    const int n_eq = in_sizes[0];   // 262144
    const int n_b  = in_sizes[1];   // 8192

    __bf16* Wh = (__bf16*)d_ws;                    // 3*256*256 bf16 = 384 KB
    __bf16* Wl = Wh + WELEM;                       // another 384 KB

    prep_w<<<WELEM / 256, 256, 0, stream>>>(W1, W2, W3, Wh, Wl);

    pinn_eq_mfma<<<n_eq / MPTS, 256, 0, stream>>>(
        xe, W0, b0, b1, b2, b3, W4, Wh, Wl, out);

    pinn_bnd_kernel<<<n_b / BP, 256, 0, stream>>>(
        xb, W0, b0, W1, b1, W2, b2, W3, b3, W4, b4, out + n_eq);
}

// Round 4
// 971.538 us; speedup vs baseline: 3.5761x; 1.4426x over previous
//
#include <hip/hip_runtime.h>

// PoissonPinn via 2nd-order forward-mode jet, hidden GEMMs on bf16 MFMA
// with hi/lo split-precision (3 MFMA terms: Ah*Bh + Ah*Bl + Al*Bh).
//
// Round-4 change vs round-3:
//  * __launch_bounds__(256, 2) on the MFMA kernel. Round-3's (256,3) capped
//    the unified VGPR file at ~170/wave (84 arch VGPRs after the AGPR split),
//    which spilled the B double-buffer to scratch: rocprof showed 1.5 GB
//    WRITE_SIZE / 650 MB FETCH_SIZE of pure spill traffic inside the K-loop.
//    (256,2) gives 256 regs/wave: 48 acc + 64 B-dbuf + 24 A + misc fits, no
//    spill. 2 blocks/CU is enough: B is double-buffered and coalesced, A is
//    prefetched, so each wave issues 36-MFMA bursts with little stalling.

constexpr int HID   = 256;
constexpr int MPTS  = 16;              // points per block (eq kernel)
constexpr int LDP   = HID + 8;         // padded LDS row stride (bf16 elems)
constexpr int WELEM = 3 * HID * HID;   // elems per split array in ws

typedef __bf16 bf16x8 __attribute__((ext_vector_type(8)));
typedef float  f32x4  __attribute__((ext_vector_type(4)));

__device__ __forceinline__ float fast_tanh(float x) {
    float e = __expf(2.0f * x);
    return 1.0f - 2.0f / (e + 1.0f);
}

// ---- prep: W1..W3 (fp32 [k][n]) -> bf16 hi/lo in fragment order ----
// Wf[l][n0][ks][lane][j]: lane=q*16+m reads W[k=ks*32+q*8+j][n=n0*16+m]
__global__ void prep_w(const float* __restrict__ W1,
                       const float* __restrict__ W2,
                       const float* __restrict__ W3,
                       __bf16* __restrict__ Wh, __bf16* __restrict__ Wl) {
    const int idx = blockIdx.x * 256 + threadIdx.x;   // 0 .. WELEM-1
    const int l   = idx >> 16;
    const int r   = idx & 0xFFFF;
    const int n0  = r >> 12;
    const int ks  = (r >> 9) & 7;
    const int ln  = (r >> 3) & 63;
    const int j   = r & 7;
    const int mm  = ln & 15;
    const int qq  = ln >> 4;
    const int k   = ks * 32 + qq * 8 + j;
    const int n   = n0 * 16 + mm;
    const float* W = (l == 0) ? W1 : (l == 1) ? W2 : W3;
    const float w  = W[k * HID + n];
    const __bf16 hi = (__bf16)w;
    Wh[idx] = hi;
    Wl[idx] = (__bf16)(w - (float)hi);
}

__global__ __launch_bounds__(256, 2)
void pinn_eq_mfma(const float* __restrict__ x,
                  const float* __restrict__ W0, const float* __restrict__ b0,
                  const float* __restrict__ b1, const float* __restrict__ b2,
                  const float* __restrict__ b3, const float* __restrict__ W4,
                  const __bf16* __restrict__ Wh, const __bf16* __restrict__ Wl,
                  float* __restrict__ out)
{
    __shared__ __align__(16) __bf16 Hh[3 * MPTS][LDP];
    __shared__ __align__(16) __bf16 Hl[3 * MPTS][LDP];

    const int tid  = threadIdx.x;
    const int lane = tid & 63;
    const int wv   = tid >> 6;
    const int m    = lane & 15;     // A-frag row / C col
    const int q    = lane >> 4;     // quad
    const int pb   = blockIdx.x * MPTS;

    bf16x8 AH[3], AL[3], BH0[4], BL0[4], BH1[4], BL1[4];
    f32x4  accv[4], accd[4], accs[4];

    auto loadB = [&](bf16x8* BH, bf16x8* BL,
                     const __bf16* whB, const __bf16* wlB, int ks) {
        #pragma unroll
        for (int nt = 0; nt < 4; ++nt) {
            const int off = ((wv * 4 + nt) * 8 + ks) * 512 + lane * 8;
            BH[nt] = *(const bf16x8*)(whB + off);
            BL[nt] = *(const bf16x8*)(wlB + off);
        }
    };
    auto loadA = [&](int ks) {
        const int kk = ks * 32 + q * 8;
        #pragma unroll
        for (int mt = 0; mt < 3; ++mt) {
            AH[mt] = *(const bf16x8*)&Hh[mt * MPTS + m][kk];
            AL[mt] = *(const bf16x8*)&Hl[mt * MPTS + m][kk];
        }
    };
    auto mfma36 = [&](bf16x8* BH, bf16x8* BL) {
        #pragma unroll
        for (int nt = 0; nt < 4; ++nt) {
            accv[nt] = __builtin_amdgcn_mfma_f32_16x16x32_bf16(AH[0], BH[nt], accv[nt], 0, 0, 0);
            accd[nt] = __builtin_amdgcn_mfma_f32_16x16x32_bf16(AH[1], BH[nt], accd[nt], 0, 0, 0);
            accs[nt] = __builtin_amdgcn_mfma_f32_16x16x32_bf16(AH[2], BH[nt], accs[nt], 0, 0, 0);
        }
        #pragma unroll
        for (int nt = 0; nt < 4; ++nt) {
            accv[nt] = __builtin_amdgcn_mfma_f32_16x16x32_bf16(AH[0], BL[nt], accv[nt], 0, 0, 0);
            accd[nt] = __builtin_amdgcn_mfma_f32_16x16x32_bf16(AH[1], BL[nt], accd[nt], 0, 0, 0);
            accs[nt] = __builtin_amdgcn_mfma_f32_16x16x32_bf16(AH[2], BL[nt], accs[nt], 0, 0, 0);
        }
        #pragma unroll
        for (int nt = 0; nt < 4; ++nt) {
            accv[nt] = __builtin_amdgcn_mfma_f32_16x16x32_bf16(AL[0], BH[nt], accv[nt], 0, 0, 0);
            accd[nt] = __builtin_amdgcn_mfma_f32_16x16x32_bf16(AL[1], BH[nt], accd[nt], 0, 0, 0);
            accs[nt] = __builtin_amdgcn_mfma_f32_16x16x32_bf16(AL[2], BH[nt], accs[nt], 0, 0, 0);
        }
    };

    // earliest possible: layer-1 ks=0 B-frags in flight during layer 0
    loadB(BH0, BL0, Wh, Wl, 0);

    // ---- layer 0: col c = tid, all 16 points ----
    {
        const int   c  = tid;
        const float w  = W0[c];
        const float bb = b0[c];
        #pragma unroll
        for (int p = 0; p < MPTS; ++p) {
            const float xv = x[pb + p];
            const float v  = fast_tanh(xv * w + bb);
            const float s2 = 1.0f - v * v;
            const float d  = s2 * w;
            const float s  = -2.0f * v * s2 * w * w;
            const __bf16 vh = (__bf16)v;  const __bf16 vl = (__bf16)(v - (float)vh);
            const __bf16 dh = (__bf16)d;  const __bf16 dl = (__bf16)(d - (float)dh);
            const __bf16 sh = (__bf16)s;  const __bf16 sl = (__bf16)(s - (float)sh);
            Hh[p][c]            = vh;  Hl[p][c]            = vl;
            Hh[MPTS + p][c]     = dh;  Hl[MPTS + p][c]     = dl;
            Hh[2 * MPTS + p][c] = sh;  Hl[2 * MPTS + p][c] = sl;
        }
    }
    __syncthreads();

    const float* bias[3] = {b1, b2, b3};

    for (int l = 0; l < 3; ++l) {
        const __bf16* __restrict__ whB = Wh + l * HID * HID;
        const __bf16* __restrict__ wlB = Wl + l * HID * HID;

        #pragma unroll
        for (int nt = 0; nt < 4; ++nt) {
            accv[nt] = (f32x4)0.0f;
            accd[nt] = (f32x4)0.0f;
            accs[nt] = (f32x4)0.0f;
        }

        loadA(0);
        #pragma unroll 1
        for (int ks = 0; ks < 8; ks += 2) {
            loadB(BH1, BL1, whB, wlB, ks + 1);       // prefetch odd step
            mfma36(BH0, BL0);
            loadA(ks + 1);
            if (ks + 2 < 8) loadB(BH0, BL0, whB, wlB, ks + 2);  // prefetch even
            mfma36(BH1, BL1);
            if (ks + 2 < 8) loadA(ks + 2);
        }

        // prefetch next layer's first B-frags; latency hides behind epilogue
        if (l < 2) loadB(BH0, BL0, whB + HID * HID, wlB + HID * HID, 0);

        // ---- jet epilogue (register-only), then LDS writeback ----
        const float* __restrict__ bvec = bias[l];
        float nv[4][4], nd[4][4], ns[4][4];
        #pragma unroll
        for (int nt = 0; nt < 4; ++nt) {
            const int col = (wv * 4 + nt) * 16 + m;
            const float bb = bvec[col];
            #pragma unroll
            for (int r = 0; r < 4; ++r) {
                const float zv = accv[nt][r] + bb;
                const float zd = accd[nt][r];
                const float zs = accs[nt][r];
                const float v  = fast_tanh(zv);
                const float s2 = 1.0f - v * v;
                nv[nt][r] = v;
                nd[nt][r] = s2 * zd;
                ns[nt][r] = s2 * zs - 2.0f * v * s2 * zd * zd;
            }
        }
        __syncthreads();   // all waves done READING H for this layer
        #pragma unroll
        for (int nt = 0; nt < 4; ++nt) {
            const int col = (wv * 4 + nt) * 16 + m;
            #pragma unroll
            for (int r = 0; r < 4; ++r) {
                const int pt = q * 4 + r;
                const float v = nv[nt][r], d = nd[nt][r], s = ns[nt][r];
                const __bf16 vh = (__bf16)v;  const __bf16 vl = (__bf16)(v - (float)vh);
                const __bf16 dh = (__bf16)d;  const __bf16 dl = (__bf16)(d - (float)dh);
                const __bf16 sh = (__bf16)s;  const __bf16 sl = (__bf16)(s - (float)sh);
                Hh[pt][col]            = vh;  Hl[pt][col]            = vl;
                Hh[MPTS + pt][col]     = dh;  Hl[MPTS + pt][col]     = dl;
                Hh[2 * MPTS + pt][col] = sh;  Hl[2 * MPTS + pt][col] = sl;
            }
        }
        __syncthreads();   // writes visible before next layer / final dot
    }

    // ---- final: d2u[pt] = sum_j h''[pt][j] * W4[j] ----
    {
        const int pt = tid >> 4;
        const int cc = tid & 15;
        float acc = 0.0f;
        #pragma unroll
        for (int j = 0; j < 16; ++j) {
            const int col = cc * 16 + j;
            const float hv = (float)Hh[2 * MPTS + pt][col] + (float)Hl[2 * MPTS + pt][col];
            acc = fmaf(hv, W4[col], acc);
        }
        #pragma unroll
        for (int off = 8; off > 0; off >>= 1)
            acc += __shfl_down(acc, off, 64);
        if (cc == 0) out[pb + pt] = acc;
    }
}

// ---- boundary: plain fp32 vector forward (tiny: 8192 points) ----
constexpr int BPW = 4;
constexpr int BP  = 16;

__global__ __launch_bounds__(256, 3)
void pinn_bnd_kernel(const float* __restrict__ x,
                     const float* __restrict__ W0, const float* __restrict__ b0,
                     const float* __restrict__ W1, const float* __restrict__ b1,
                     const float* __restrict__ W2, const float* __restrict__ b2,
                     const float* __restrict__ W3, const float* __restrict__ b3,
                     const float* __restrict__ W4, const float* __restrict__ b4,
                     float* __restrict__ out)
{
    __shared__ float HV[BP][HID];

    const int lane  = threadIdx.x & 63;
    const int wv    = threadIdx.x >> 6;
    const int rbase = wv * BPW;
    const int pbase = blockIdx.x * BP + rbase;

    #pragma unroll
    for (int c = 0; c < 4; ++c) {
        const int   j  = lane + 64 * c;
        const float w  = W0[j];
        const float bb = b0[j];
        #pragma unroll
        for (int p = 0; p < BPW; ++p)
            HV[rbase + p][j] = fast_tanh(x[pbase + p] * w + bb);
    }
    __syncthreads();

    const float* Ws[3] = {W1, W2, W3};
    const float* bs[3] = {b1, b2, b3};

    #pragma unroll
    for (int l = 0; l < 3; ++l) {
        const float* __restrict__ W = Ws[l];
        const float* __restrict__ b = bs[l];

        float zv[BPW][4];
        #pragma unroll
        for (int p = 0; p < BPW; ++p)
            #pragma unroll
            for (int c = 0; c < 4; ++c)
                zv[p][c] = b[lane + 64 * c];

        for (int i = 0; i < HID; i += 4) {
            float w[4][4];
            #pragma unroll
            for (int qq = 0; qq < 4; ++qq)
                #pragma unroll
                for (int c = 0; c < 4; ++c)
                    w[qq][c] = W[(i + qq) * HID + lane + 64 * c];

            #pragma unroll
            for (int p = 0; p < BPW; ++p) {
                const float4 av = *(const float4*)&HV[rbase + p][i];
                #pragma unroll
                for (int qq = 0; qq < 4; ++qq) {
                    const float a_v = ((const float*)&av)[qq];
                    #pragma unroll
                    for (int c = 0; c < 4; ++c)
                        zv[p][c] = fmaf(a_v, w[qq][c], zv[p][c]);
                }
            }
        }
        __syncthreads();

        #pragma unroll
        for (int p = 0; p < BPW; ++p)
            #pragma unroll
            for (int c = 0; c < 4; ++c)
                HV[rbase + p][lane + 64 * c] = fast_tanh(zv[p][c]);
        __syncthreads();
    }

    const float bias4 = b4[0];
    #pragma unroll
    for (int p = 0; p < BPW; ++p) {
        float acc = 0.0f;
        #pragma unroll
        for (int c = 0; c < 4; ++c) {
            const int j = lane + 64 * c;
            acc = fmaf(HV[rbase + p][j], W4[j], acc);
        }
        #pragma unroll
        for (int off = 32; off > 0; off >>= 1)
            acc += __shfl_down(acc, off, 64);
        if (lane == 0) out[pbase + p] = acc + bias4;
    }
}

extern "C" void kernel_launch(void* const* d_in, const int* in_sizes, int n_in,
                              void* d_out, int out_size, void* d_ws, size_t ws_size,
                              hipStream_t stream) {
    const float* xe = (const float*)d_in[0];
    const float* xb = (const float*)d_in[1];
    const float* W0 = (const float*)d_in[2];
    const float* b0 = (const float*)d_in[3];
    const float* W1 = (const float*)d_in[4];
    const float* b1 = (const float*)d_in[5];
    const float* W2 = (const float*)d_in[6];
    const float* b2 = (const float*)d_in[7];
    const float* W3 = (const float*)d_in[8];
    const float* b3 = (const float*)d_in[9];
    const float* W4 = (const float*)d_in[10];
    const float* b4 = (const float*)d_in[11];
    float* out = (float*)d_out;

    const int n_eq = in_sizes[0];   // 262144
    const int n_b  = in_sizes[1];   // 8192

    __bf16* Wh = (__bf16*)d_ws;                    // 3*256*256 bf16 = 384 KB
    __bf16* Wl = Wh + WELEM;                       // another 384 KB

    prep_w<<<WELEM / 256, 256, 0, stream>>>(W1, W2, W3, Wh, Wl);

    pinn_eq_mfma<<<n_eq / MPTS, 256, 0, stream>>>(
        xe, W0, b0, b1, b2, b3, W4, Wh, Wl, out);

    pinn_bnd_kernel<<<n_b / BP, 256, 0, stream>>>(
        xb, W0, b0, W1, b1, W2, b2, W3, b3, W4, b4, out + n_eq);
}